// Round 4
// baseline (125.353 us; speedup 1.0000x reference)
//
#include <hip/hip_runtime.h>
#include <hip/hip_bf16.h>

#define B 16
#define S 2048
#define VOCAB 32000
#define D_EMB 256
#define D_MODEL 512
#define LN_EPS 1e-5f

using bf16x8 = __attribute__((ext_vector_type(8))) short;
using f32x4  = __attribute__((ext_vector_type(4))) float;

static __device__ __forceinline__ unsigned short f2bf(float f) {
    __hip_bfloat16 h = __float2bfloat16(f);   // RNE
    return *reinterpret_cast<unsigned short*>(&h);
}

// ---------------------------------------------------------------------------
// Kernel A: Wk_bf16[b][m][k] = sum_j Wb[m,k,j] * king_table[kid[b], j]
// grid = 512 (one block per m), 256 threads (one per k a.k.a. i).
// kid forced to SGPR via readfirstlane -> king_table loads are uniform
// (s_load on the SMEM pipe, no VMEM storm). Wb streamed NT.
// ---------------------------------------------------------------------------
#define ACH 32

__global__ __launch_bounds__(256) void wk_kernel(
    const float* __restrict__ Wb,
    const float* __restrict__ king_table,
    const int* __restrict__ king_id,
    unsigned short* __restrict__ Wk)
{
    __shared__ float wT[ACH][257];   // transposed chunk: wT[jj][i], +1 pad
    const int m = blockIdx.x;
    const int i = threadIdx.x;

    int kid[B];
#pragma unroll
    for (int b = 0; b < B; ++b)
        kid[b] = __builtin_amdgcn_readfirstlane(king_id[b]);   // -> SGPR

    float acc[B];
#pragma unroll
    for (int b = 0; b < B; ++b) acc[b] = 0.0f;

    const float* wrow = Wb + (size_t)m * (D_EMB * D_EMB);

    for (int j0 = 0; j0 < D_EMB; j0 += ACH) {
        __syncthreads();
        // coalesced NT load of Wb[m][:, j0:j0+32] -> transposed LDS
        // 256 rows x 8 float4 = 2048 float4, 256 threads x 8 iters
#pragma unroll
        for (int it = 0; it < 8; ++it) {
            int idx = it * 256 + i;
            int row = idx >> 3;       // i index [0,256)
            int c4  = idx & 7;        // which float4 within 32-wide chunk
            f32x4 v = __builtin_nontemporal_load(
                (const f32x4*)(wrow + row * D_EMB + j0 + c4 * 4));
            wT[c4 * 4 + 0][row] = v.x;
            wT[c4 * 4 + 1][row] = v.y;
            wT[c4 * 4 + 2][row] = v.z;
            wT[c4 * 4 + 3][row] = v.w;
        }
        __syncthreads();

#pragma unroll
        for (int jj = 0; jj < ACH / 4; ++jj) {
            float w0 = wT[jj * 4 + 0][i];
            float w1 = wT[jj * 4 + 1][i];
            float w2 = wT[jj * 4 + 2][i];
            float w3 = wT[jj * 4 + 3][i];
            int j = j0 + jj * 4;
#pragma unroll
            for (int b = 0; b < B; ++b) {
                f32x4 kv = *(const f32x4*)(king_table + (size_t)kid[b] * D_EMB + j);
                acc[b] = fmaf(w0, kv.x, acc[b]);
                acc[b] = fmaf(w1, kv.y, acc[b]);
                acc[b] = fmaf(w2, kv.z, acc[b]);
                acc[b] = fmaf(w3, kv.w, acc[b]);
            }
        }
    }

#pragma unroll
    for (int b = 0; b < B; ++b)
        Wk[((size_t)b * D_MODEL + m) * D_EMB + i] = f2bf(acc[b]);
}

// ---------------------------------------------------------------------------
// Kernel B (MFMA): x[b,s,m] = sum_k tok[b,s,k]*Wk[b,m,k] + bb[m]; LN over m.
// grid = (S/64, B), 512 threads = 8 waves.
// Block tile: 64 s-rows x 512 m-cols (full m-span -> LN is block-local).
// Wave w owns m-slice [w*64, w*64+64): M_rep=4 (16-row frags), N_rep=4.
// A (tok) staged once in LDS as bf16 [64][264]; B (Wk bf16) direct global.
// mfma_f32_16x16x32_bf16 frag layout: A/B lane l -> row/col = l&15,
// k = (l>>4)*8 + j (16B contiguous). C/D: col = l&15, row = (l>>4)*4 + reg.
// ---------------------------------------------------------------------------
#define TSB 64

__global__ __launch_bounds__(512) void gemm_ln_mfma(
    const int* __restrict__ seq,
    const int* __restrict__ king_id,
    const float* __restrict__ token_tables,
    const unsigned short* __restrict__ Wk,
    const float* __restrict__ bb,
    const float* __restrict__ gamma,
    const float* __restrict__ beta,
    float* __restrict__ out)
{
    __shared__ unsigned short tokL[TSB][264];   // 64 x (256+8 pad) bf16 = 33 KB
    __shared__ float red_sum[8][TSB];
    __shared__ float red_sq[8][TSB];
    __shared__ float stats[2][TSB];             // [0]=mean, [1]=rstd

    const int b    = blockIdx.y;
    const int s0   = blockIdx.x * TSB;
    const int t    = threadIdx.x;
    const int lane = t & 63;
    const int wave = t >> 6;
    const int lr   = lane & 15;     // frag row/col index
    const int kg   = lane >> 4;     // k-group (0..3)

    const int kb = king_id[b];
    const float* ttab = token_tables + (size_t)kb * VOCAB * D_EMB;

    // ---- stage gathered tok tile: fp32 global -> bf16 LDS ----
    {
        int row = t >> 3;            // 0..63
        int ck  = (t & 7) * 32;      // k chunk start (32 floats)
        int tokidx = seq[b * S + s0 + row];
        const float4* src = (const float4*)(ttab + (size_t)tokidx * D_EMB + ck);
#pragma unroll
        for (int u = 0; u < 4; ++u) {
            float4 v0 = src[u * 2 + 0];
            float4 v1 = src[u * 2 + 1];
            union { unsigned short us[8]; uint4 q; } pk;
            pk.us[0] = f2bf(v0.x); pk.us[1] = f2bf(v0.y);
            pk.us[2] = f2bf(v0.z); pk.us[3] = f2bf(v0.w);
            pk.us[4] = f2bf(v1.x); pk.us[5] = f2bf(v1.y);
            pk.us[6] = f2bf(v1.z); pk.us[7] = f2bf(v1.w);
            *(uint4*)&tokL[row][ck + u * 8] = pk.q;
        }
    }
    __syncthreads();

    // ---- fragment pointers ----
    const int m0 = wave * 64;                  // wave's m-slice base
    const uint4* aptr[4];
    const uint4* bptr[4];
#pragma unroll
    for (int mf = 0; mf < 4; ++mf)
        aptr[mf] = (const uint4*)&tokL[mf * 16 + lr][kg * 8];
#pragma unroll
    for (int nf = 0; nf < 4; ++nf) {
        int col = m0 + nf * 16 + lr;
        bptr[nf] = (const uint4*)(Wk + ((size_t)(b * D_MODEL + col)) * D_EMB + kg * 8);
    }

    f32x4 acc[4][4] = {};

    // ---- K loop: 8 steps of K=32, fully unrolled ----
#pragma unroll
    for (int step = 0; step < 8; ++step) {
        bf16x8 af[4], bfr[4];
#pragma unroll
        for (int mf = 0; mf < 4; ++mf) {
            uint4 q = aptr[mf][step * 4];
            af[mf] = __builtin_bit_cast(bf16x8, q);
        }
#pragma unroll
        for (int nf = 0; nf < 4; ++nf) {
            uint4 q = bptr[nf][step * 4];
            bfr[nf] = __builtin_bit_cast(bf16x8, q);
        }
#pragma unroll
        for (int mf = 0; mf < 4; ++mf)
#pragma unroll
            for (int nf = 0; nf < 4; ++nf)
                acc[mf][nf] = __builtin_amdgcn_mfma_f32_16x16x32_bf16(
                    af[mf], bfr[nf], acc[mf][nf], 0, 0, 0);
    }

    // ---- epilogue: bias, block-wide LN stats ----
    float bbv[4], gv[4], bv[4];
#pragma unroll
    for (int nf = 0; nf < 4; ++nf) {
        int col = m0 + nf * 16 + lr;
        bbv[nf] = bb[col];
        gv[nf]  = gamma[col];
        bv[nf]  = beta[col];
    }

#pragma unroll
    for (int mf = 0; mf < 4; ++mf) {
#pragma unroll
        for (int r = 0; r < 4; ++r) {
            float sum = 0.0f, sq = 0.0f;
#pragma unroll
            for (int nf = 0; nf < 4; ++nf) {
                float v = acc[mf][nf][r] + bbv[nf];
                acc[mf][nf][r] = v;
                sum += v;
                sq  += v * v;
            }
#pragma unroll
            for (int off = 1; off < 16; off <<= 1) {
                sum += __shfl_xor(sum, off);
                sq  += __shfl_xor(sq, off);
            }
            if (lr == 0) {
                int row = mf * 16 + kg * 4 + r;
                red_sum[wave][row] = sum;
                red_sq[wave][row]  = sq;
            }
        }
    }
    __syncthreads();

    if (t < TSB) {
        float s = 0.0f, q = 0.0f;
#pragma unroll
        for (int w = 0; w < 8; ++w) { s += red_sum[w][t]; q += red_sq[w][t]; }
        float mean = s * (1.0f / D_MODEL);
        float var  = q * (1.0f / D_MODEL) - mean * mean;
        stats[0][t] = mean;
        stats[1][t] = rsqrtf(var + LN_EPS);
    }
    __syncthreads();

    // ---- normalize + nontemporal store (keep L2 for Wk/tok) ----
#pragma unroll
    for (int mf = 0; mf < 4; ++mf) {
#pragma unroll
        for (int r = 0; r < 4; ++r) {
            int row = mf * 16 + kg * 4 + r;
            float mean = stats[0][row];
            float rstd = stats[1][row];
            float* op = out + ((size_t)b * S + s0 + row) * D_MODEL + m0 + lr;
#pragma unroll
            for (int nf = 0; nf < 4; ++nf) {
                float o = (acc[mf][nf][r] - mean) * rstd * gv[nf] + bv[nf];
                __builtin_nontemporal_store(o, op + nf * 16);
            }
        }
    }
}

// ---------------------------------------------------------------------------
extern "C" void kernel_launch(void* const* d_in, const int* in_sizes, int n_in,
                              void* d_out, int out_size, void* d_ws, size_t ws_size,
                              hipStream_t stream)
{
    const int*   seq          = (const int*)d_in[0];
    const int*   king_id      = (const int*)d_in[1];
    const float* token_tables = (const float*)d_in[2];
    const float* Wb           = (const float*)d_in[3];
    const float* bb           = (const float*)d_in[4];
    const float* king_table   = (const float*)d_in[5];
    const float* gamma        = (const float*)d_in[6];
    const float* beta         = (const float*)d_in[7];
    float* out = (float*)d_out;

    unsigned short* Wk = (unsigned short*)d_ws;   // B*D_MODEL*D_EMB bf16 = 4 MB

    wk_kernel<<<dim3(D_MODEL), dim3(256), 0, stream>>>(Wb, king_table, king_id, Wk);
    gemm_ln_mfma<<<dim3(S / TSB, B), dim3(512), 0, stream>>>(
        seq, king_id, token_tables, Wk, bb, gamma, beta, out);
}

// Round 5
// 68.726 us; speedup vs baseline: 1.8240x; 1.8240x over previous
//
#include <hip/hip_runtime.h>
#include <hip/hip_bf16.h>

#define B 16
#define S 2048
#define VOCAB 32000
#define D_EMB 256
#define D_MODEL 512
#define LN_EPS 1e-5f

using bf16x8 = __attribute__((ext_vector_type(8))) short;
using f32x4  = __attribute__((ext_vector_type(4))) float;

static __device__ __forceinline__ unsigned short f2bf(float f) {
    __hip_bfloat16 h = __float2bfloat16(f);   // RNE
    return *reinterpret_cast<unsigned short*>(&h);
}

static __device__ __forceinline__ bf16x8 pack8(f32x4 v0, f32x4 v1) {
    union { unsigned short us[8]; bf16x8 v; } pk;
    pk.us[0] = f2bf(v0.x); pk.us[1] = f2bf(v0.y);
    pk.us[2] = f2bf(v0.z); pk.us[3] = f2bf(v0.w);
    pk.us[4] = f2bf(v1.x); pk.us[5] = f2bf(v1.y);
    pk.us[6] = f2bf(v1.z); pk.us[7] = f2bf(v1.w);
    return pk.v;
}

// ---------------------------------------------------------------------------
// Kernel A (MFMA): Wk[b][r] = sum_j Wb[r][j] * kemb[b][j],  r = m*256+i.
// GEMM (131072 x 256) @ (256 x 16): B-dim = 16 = exactly one fragment width.
// kemb B-fragments live in 32 VGPRs for the whole kernel (loaded once).
// Wb rows feed A-fragments directly from global: lane (lr,kg) reads
// row rbase+mf*16+lr, j in [step*32+kg*8, +8) -> 2x dwordx4, coalesced.
// C/D: col = lane&15 = b, row = kg*4+reg -> pack 4 bf16, one 8B store.
// grid = 512 blocks x 256 thr (4 waves); wave handles 64 rows (4 frags).
// No LDS, no barriers, no operand reload: pure 134 MB Wb stream.
// ---------------------------------------------------------------------------
__global__ __launch_bounds__(256) void wk_mfma(
    const float* __restrict__ Wb,
    const float* __restrict__ king_table,
    const int* __restrict__ king_id,
    unsigned short* __restrict__ Wk)
{
    const int t    = threadIdx.x;
    const int lane = t & 63;
    const int wave = t >> 6;
    const int lr   = lane & 15;     // b index (B-frag col) / row index (A-frag)
    const int kg   = lane >> 4;     // k-group

    // ---- kemb B-operand fragments, register-resident ----
    const int kid = king_id[lr];
    const float* kp = king_table + (size_t)kid * D_EMB + kg * 8;
    bf16x8 bemb[8];
#pragma unroll
    for (int step = 0; step < 8; ++step) {
        f32x4 v0 = *(const f32x4*)(kp + step * 32);
        f32x4 v1 = *(const f32x4*)(kp + step * 32 + 4);
        bemb[step] = pack8(v0, v1);
    }

    const int rbase = (blockIdx.x * 4 + wave) * 64;

#pragma unroll
    for (int mf = 0; mf < 4; ++mf) {
        const float* arow = Wb + (size_t)(rbase + mf * 16 + lr) * D_EMB + kg * 8;
        f32x4 acc = {};
#pragma unroll
        for (int step = 0; step < 8; ++step) {
            f32x4 v0 = *(const f32x4*)(arow + step * 32);
            f32x4 v1 = *(const f32x4*)(arow + step * 32 + 4);
            acc = __builtin_amdgcn_mfma_f32_16x16x32_bf16(
                pack8(v0, v1), bemb[step], acc, 0, 0, 0);
        }
        // lane holds C[kg*4 + r][b=lr], r=0..3 -> 4 consecutive Wk rows
        union { unsigned short us[4]; uint2 q; } st;
        st.us[0] = f2bf(acc[0]); st.us[1] = f2bf(acc[1]);
        st.us[2] = f2bf(acc[2]); st.us[3] = f2bf(acc[3]);
        *(uint2*)(Wk + (size_t)lr * (D_MODEL * D_EMB) + rbase + mf * 16 + kg * 4) = st.q;
    }
}

// ---------------------------------------------------------------------------
// Kernel B (MFMA): x[b,s,m] = sum_k tok[b,s,k]*Wk[b,m,k] + bb[m]; LN over m.
// grid = (S/64, B), 512 threads = 8 waves.  (Identical to the proven R2.)
// ---------------------------------------------------------------------------
#define TSB 64

__global__ __launch_bounds__(512) void gemm_ln_mfma(
    const int* __restrict__ seq,
    const int* __restrict__ king_id,
    const float* __restrict__ token_tables,
    const unsigned short* __restrict__ Wk,
    const float* __restrict__ bb,
    const float* __restrict__ gamma,
    const float* __restrict__ beta,
    float* __restrict__ out)
{
    __shared__ unsigned short tokL[TSB][264];   // 64 x (256+8 pad) bf16 = 33 KB
    __shared__ float red_sum[8][TSB];
    __shared__ float red_sq[8][TSB];
    __shared__ float stats[2][TSB];             // [0]=mean, [1]=rstd

    const int b    = blockIdx.y;
    const int s0   = blockIdx.x * TSB;
    const int t    = threadIdx.x;
    const int lane = t & 63;
    const int wave = t >> 6;
    const int lr   = lane & 15;     // frag row/col index
    const int kg   = lane >> 4;     // k-group (0..3)

    const int kb = king_id[b];
    const float* ttab = token_tables + (size_t)kb * VOCAB * D_EMB;

    // ---- stage gathered tok tile: fp32 global -> bf16 LDS ----
    {
        int row = t >> 3;            // 0..63
        int ck  = (t & 7) * 32;      // k chunk start (32 floats)
        int tokidx = seq[b * S + s0 + row];
        const float4* src = (const float4*)(ttab + (size_t)tokidx * D_EMB + ck);
#pragma unroll
        for (int u = 0; u < 4; ++u) {
            float4 v0 = src[u * 2 + 0];
            float4 v1 = src[u * 2 + 1];
            union { unsigned short us[8]; uint4 q; } pk;
            pk.us[0] = f2bf(v0.x); pk.us[1] = f2bf(v0.y);
            pk.us[2] = f2bf(v0.z); pk.us[3] = f2bf(v0.w);
            pk.us[4] = f2bf(v1.x); pk.us[5] = f2bf(v1.y);
            pk.us[6] = f2bf(v1.z); pk.us[7] = f2bf(v1.w);
            *(uint4*)&tokL[row][ck + u * 8] = pk.q;
        }
    }
    __syncthreads();

    // ---- fragment pointers ----
    const int m0 = wave * 64;                  // wave's m-slice base
    const uint4* aptr[4];
    const uint4* bptr[4];
#pragma unroll
    for (int mf = 0; mf < 4; ++mf)
        aptr[mf] = (const uint4*)&tokL[mf * 16 + lr][kg * 8];
#pragma unroll
    for (int nf = 0; nf < 4; ++nf) {
        int col = m0 + nf * 16 + lr;
        bptr[nf] = (const uint4*)(Wk + ((size_t)(b * D_MODEL + col)) * D_EMB + kg * 8);
    }

    f32x4 acc[4][4] = {};

    // ---- K loop: 8 steps of K=32, fully unrolled ----
#pragma unroll
    for (int step = 0; step < 8; ++step) {
        bf16x8 af[4], bfr[4];
#pragma unroll
        for (int mf = 0; mf < 4; ++mf) {
            uint4 q = aptr[mf][step * 4];
            af[mf] = __builtin_bit_cast(bf16x8, q);
        }
#pragma unroll
        for (int nf = 0; nf < 4; ++nf) {
            uint4 q = bptr[nf][step * 4];
            bfr[nf] = __builtin_bit_cast(bf16x8, q);
        }
#pragma unroll
        for (int mf = 0; mf < 4; ++mf)
#pragma unroll
            for (int nf = 0; nf < 4; ++nf)
                acc[mf][nf] = __builtin_amdgcn_mfma_f32_16x16x32_bf16(
                    af[mf], bfr[nf], acc[mf][nf], 0, 0, 0);
    }

    // ---- epilogue: bias, block-wide LN stats ----
    float bbv[4], gv[4], bv[4];
#pragma unroll
    for (int nf = 0; nf < 4; ++nf) {
        int col = m0 + nf * 16 + lr;
        bbv[nf] = bb[col];
        gv[nf]  = gamma[col];
        bv[nf]  = beta[col];
    }

#pragma unroll
    for (int mf = 0; mf < 4; ++mf) {
#pragma unroll
        for (int r = 0; r < 4; ++r) {
            float sum = 0.0f, sq = 0.0f;
#pragma unroll
            for (int nf = 0; nf < 4; ++nf) {
                float v = acc[mf][nf][r] + bbv[nf];
                acc[mf][nf][r] = v;
                sum += v;
                sq  += v * v;
            }
#pragma unroll
            for (int off = 1; off < 16; off <<= 1) {
                sum += __shfl_xor(sum, off);
                sq  += __shfl_xor(sq, off);
            }
            if (lr == 0) {
                int row = mf * 16 + kg * 4 + r;
                red_sum[wave][row] = sum;
                red_sq[wave][row]  = sq;
            }
        }
    }
    __syncthreads();

    if (t < TSB) {
        float s = 0.0f, q = 0.0f;
#pragma unroll
        for (int w = 0; w < 8; ++w) { s += red_sum[w][t]; q += red_sq[w][t]; }
        float mean = s * (1.0f / D_MODEL);
        float var  = q * (1.0f / D_MODEL) - mean * mean;
        stats[0][t] = mean;
        stats[1][t] = rsqrtf(var + LN_EPS);
    }
    __syncthreads();

    // ---- normalize + store ----
#pragma unroll
    for (int mf = 0; mf < 4; ++mf) {
#pragma unroll
        for (int r = 0; r < 4; ++r) {
            int row = mf * 16 + kg * 4 + r;
            float mean = stats[0][row];
            float rstd = stats[1][row];
            float* op = out + ((size_t)b * S + s0 + row) * D_MODEL + m0 + lr;
#pragma unroll
            for (int nf = 0; nf < 4; ++nf)
                op[nf * 16] = (acc[mf][nf][r] - mean) * rstd * gv[nf] + bv[nf];
        }
    }
}

// ---------------------------------------------------------------------------
extern "C" void kernel_launch(void* const* d_in, const int* in_sizes, int n_in,
                              void* d_out, int out_size, void* d_ws, size_t ws_size,
                              hipStream_t stream)
{
    const int*   seq          = (const int*)d_in[0];
    const int*   king_id      = (const int*)d_in[1];
    const float* token_tables = (const float*)d_in[2];
    const float* Wb           = (const float*)d_in[3];
    const float* bb           = (const float*)d_in[4];
    const float* king_table   = (const float*)d_in[5];
    const float* gamma        = (const float*)d_in[6];
    const float* beta         = (const float*)d_in[7];
    float* out = (float*)d_out;

    unsigned short* Wk = (unsigned short*)d_ws;   // B*D_MODEL*D_EMB bf16 = 4 MB

    wk_mfma<<<dim3((D_MODEL * D_EMB) / 256), dim3(256), 0, stream>>>(
        Wb, king_table, king_id, Wk);
    gemm_ln_mfma<<<dim3(S / TSB, B), dim3(512), 0, stream>>>(
        seq, king_id, token_tables, Wk, bb, gamma, beta, out);
}